// Round 1
// 470.029 us; speedup vs baseline: 1.1482x; 1.1482x over previous
//
#include <hip/hip_runtime.h>
#include <math.h>

#define EPS 1e-6f

// ws layout (floats):
//   h      @ 0       [2][1024]
//   qkv    @ 2048    5 layers x [2][3072]   (q|k|v concatenated per row)
//   gu     @ 43008   5 layers x [2][2][4096] (gate/up)

__device__ __forceinline__ float red32(float v) {
#pragma unroll
    for (int m = 16; m >= 1; m >>= 1) v += __shfl_xor(v, m, 64);
    return v;
}

// ---------------- init: zero accumulators + build h ----------------
__global__ void init_kernel(const float* __restrict__ past_hidden,
                            const float* __restrict__ codec_emb,
                            const int* __restrict__ tok,
                            float* __restrict__ ws,
                            float* __restrict__ logits)
{
    size_t idx = (size_t)blockIdx.x * blockDim.x + threadIdx.x;
    size_t stride = (size_t)gridDim.x * blockDim.x;
    for (size_t i = idx; i < 30720; i += stride) ws[2048 + i] = 0.f;   // qkv x5
    for (size_t i = idx; i < 81920; i += stride) ws[43008 + i] = 0.f;  // gu x5
    for (size_t i = idx; i < 30720; i += stride) logits[i] = 0.f;      // logits out
    int t = tok[0];
    for (size_t i = idx; i < 1024; i += stride) {
        ws[i]        = past_hidden[i];
        ws[1024 + i] = codec_emb[(size_t)t * 1024 + i];
    }
}

// ---------------- generic split-K GEMV with fused (deferred) RMSNorm ----------------
// out[z][s][Nslice] += rsqrt(mean(x^2)+eps) * ((x*nw) @ W)
// D fixed at 1024. grid: (N/256, 1024/(4R), nz), block 256.
// Weight slab is prefetched into registers BEFORE touching x, so HBM streaming
// starts at cycle ~0; the norm reduction finishes after the dot product and is
// applied as a scalar to the accumulator.
template <int S, int R>
__global__ __launch_bounds__(256) void gemv_rms(
    const float* __restrict__ hbuf,   // [S][1024]
    const float* __restrict__ nw,     // [1024] rmsnorm weight
    const float* __restrict__ W0,
    const float* __restrict__ W1,
    const float* __restrict__ W2,
    size_t w_zstride,
    float* __restrict__ out,
    int out_sstride, int out_zstride, int N)
{
    __shared__ float xs[S * 1024];    // x*nw; reused as reduction scratch (4*S*256 == S*1024)
    __shared__ float sstot[S * 4];
    const int t = threadIdx.x;
    const int lane = t & 63;
    const int dp = t >> 6;

    const float* W;
    if (W1) W = (blockIdx.z == 0) ? W0 : ((blockIdx.z == 1) ? W1 : W2);
    else    W = W0 + (size_t)blockIdx.z * w_zstride;
    float* outz = out + (size_t)blockIdx.z * out_zstride;

    const int j = blockIdx.x * 256 + lane * 4;
    const int d0 = blockIdx.y * (4 * R) + dp * R;

    // 1) prefetch weight slab into registers
    float4 wreg[R];
    const float* Wp = W + (size_t)d0 * N + j;
#pragma unroll
    for (int i = 0; i < R; ++i)
        wreg[i] = *reinterpret_cast<const float4*>(Wp + (size_t)i * N);

    // 2) load x, apply nw, keep sum-of-squares in registers
    float ss[S];
    {
        float4 nw4 = *reinterpret_cast<const float4*>(nw + t * 4);
#pragma unroll
        for (int s = 0; s < S; ++s) {
            float4 xv = *reinterpret_cast<const float4*>(hbuf + s * 1024 + t * 4);
            ss[s] = xv.x * xv.x + xv.y * xv.y + xv.z * xv.z + xv.w * xv.w;
            float4 xw = make_float4(xv.x * nw4.x, xv.y * nw4.y, xv.z * nw4.z, xv.w * nw4.w);
            *reinterpret_cast<float4*>(&xs[s * 1024 + t * 4]) = xw;
        }
    }
    __syncthreads();

    // 3) dot product
    float acc[S][4];
#pragma unroll
    for (int s = 0; s < S; ++s) { acc[s][0] = acc[s][1] = acc[s][2] = acc[s][3] = 0.f; }
#pragma unroll
    for (int i = 0; i < R; ++i) {
        int dd = d0 + i;
#pragma unroll
        for (int s = 0; s < S; ++s) {
            float xv = xs[s * 1024 + dd];
            acc[s][0] += xv * wreg[i].x; acc[s][1] += xv * wreg[i].y;
            acc[s][2] += xv * wreg[i].z; acc[s][3] += xv * wreg[i].w;
        }
    }

    // 4) finish the rmsnorm sum (register/shuffle only)
#pragma unroll
    for (int s = 0; s < S; ++s) {
        float v = ss[s];
#pragma unroll
        for (int m = 32; m >= 1; m >>= 1) v += __shfl_xor(v, m, 64);
        if (lane == 0) sstot[s * 4 + dp] = v;
    }
    __syncthreads();   // xs reads done; sstot visible
    float sc[S];
#pragma unroll
    for (int s = 0; s < S; ++s) {
        float tot = sstot[s * 4 + 0] + sstot[s * 4 + 1] + sstot[s * 4 + 2] + sstot[s * 4 + 3];
        sc[s] = rsqrtf(tot / 1024.f + EPS);
    }

    // 5) cross-dp reduce + atomic add (reuse xs as scratch)
#pragma unroll
    for (int s = 0; s < S; ++s)
#pragma unroll
        for (int c = 0; c < 4; ++c)
            xs[(dp * S + s) * 256 + lane * 4 + c] = acc[s][c] * sc[s];
    __syncthreads();
    for (int o = t; o < S * 256; o += 256) {
        int s = o >> 8;
        int col = o & 255;
        float sum = 0.f;
#pragma unroll
        for (int p = 0; p < 4; ++p) sum += xs[(p * S + s) * 256 + col];
        atomicAdd(outz + (size_t)s * out_sstride + blockIdx.x * 256 + col, sum);
    }
}

// ---------------- fused attention + O-projection ----------------
// Every block redundantly recomputes the tiny 2x2 attention (pure shuffle
// reductions, hidden under the Wo register prefetch), then does its slice of
// the O-projection GEMV, residual-atomicAdd into h. Block (0,0) writes kv cache.
// grid (4, 64), block 256.
__global__ __launch_bounds__(256) void attn_o_kernel(
    const float* __restrict__ qkv,   // [2][3072]
    const float* __restrict__ qnw,   // [128]
    const float* __restrict__ knw,   // [128]
    const float* __restrict__ W,     // Wo [1024][1024]
    float* __restrict__ out,         // h [2][1024]
    float* __restrict__ kvc)         // layer kv: k at 0, v at 2048
{
    __shared__ float xs[2048];
    const int t = threadIdx.x;
    const int lane = t & 63;
    const int dp = t >> 6;
    const int j = blockIdx.x * 256 + lane * 4;
    const int d0 = blockIdx.y * 16 + dp * 4;

    // 1) prefetch Wo slab
    float4 wreg[4];
    const float* Wp = W + (size_t)d0 * 1024 + j;
#pragma unroll
    for (int i = 0; i < 4; ++i)
        wreg[i] = *reinterpret_cast<const float4*>(Wp + (size_t)i * 1024);

    // 2) attention: head = t>>5, 32 lanes per head, 4 d's per lane {g,g+32,g+64,g+96}
    const int hh = t >> 5;
    const int g = t & 31;
    float q[2][4], k[2][4], v[2][4];
#pragma unroll
    for (int s = 0; s < 2; ++s)
#pragma unroll
        for (int c = 0; c < 4; ++c) {
            int d = g + c * 32;
            q[s][c] = qkv[s * 3072 +        hh * 128 + d];
            k[s][c] = qkv[s * 3072 + 1024 + hh * 128 + d];
            v[s][c] = qkv[s * 3072 + 2048 + hh * 128 + d];
        }
    // q/k rmsnorm (reduction stays within the 32-lane head group: xor masks <= 16)
#pragma unroll
    for (int s = 0; s < 2; ++s) {
        float sq = q[s][0]*q[s][0] + q[s][1]*q[s][1] + q[s][2]*q[s][2] + q[s][3]*q[s][3];
        float sk = k[s][0]*k[s][0] + k[s][1]*k[s][1] + k[s][2]*k[s][2] + k[s][3]*k[s][3];
        sq = red32(sq); sk = red32(sk);
        float qsc = rsqrtf(sq / 128.f + EPS);
        float ksc = rsqrtf(sk / 128.f + EPS);
#pragma unroll
        for (int c = 0; c < 4; ++c) {
            q[s][c] *= qsc * qnw[g + c * 32];
            k[s][c] *= ksc * knw[g + c * 32];
        }
    }
    // RoPE: pos=0 row is identity; pos=1 uses inv_freq = 10000^{-(d&63)/64}
    // lane holds the rotate_half pair (d, d+64) locally: c0<->c2, c1<->c3
    float inv0 = powf(10000.f, -(float)g / 64.f);
    float inv1 = powf(10000.f, -(float)(g + 32) / 64.f);
    float cA = cosf(inv0), sA = sinf(inv0);
    float cB = cosf(inv1), sB = sinf(inv1);
    float q1[4] = { q[1][0]*cA - q[1][2]*sA, q[1][1]*cB - q[1][3]*sB,
                    q[1][2]*cA + q[1][0]*sA, q[1][3]*cB + q[1][1]*sB };
    float k1[4] = { k[1][0]*cA - k[1][2]*sA, k[1][1]*cB - k[1][3]*sB,
                    k[1][2]*cA + k[1][0]*sA, k[1][3]*cB + k[1][1]*sB };

    if (blockIdx.x == 0 && blockIdx.y == 0) {
#pragma unroll
        for (int c = 0; c < 4; ++c) {
            int d = g + c * 32;
            kvc[hh * 256 +       d] = k[0][c];
            kvc[hh * 256 + 128 + d] = k1[c];
            kvc[2048 + hh * 256 +       d] = v[0][c];
            kvc[2048 + hh * 256 + 128 + d] = v[1][c];
        }
    }

    float p00 = red32(q[0][0]*k[0][0] + q[0][1]*k[0][1] + q[0][2]*k[0][2] + q[0][3]*k[0][3]);
    float p01 = red32(q[0][0]*k1[0]   + q[0][1]*k1[1]   + q[0][2]*k1[2]   + q[0][3]*k1[3]);
    float p10 = red32(q1[0]*k[0][0]   + q1[1]*k[0][1]   + q1[2]*k[0][2]   + q1[3]*k[0][3]);
    float p11 = red32(q1[0]*k1[0]     + q1[1]*k1[1]     + q1[2]*k1[2]     + q1[3]*k1[3]);

    const float scale = 0.08838834764831845f; // 1/sqrt(128)
    float s00 = p00 * scale, s01 = p01 * scale - 1e9f;
    float m0 = fmaxf(s00, s01);
    float e0 = expf(s00 - m0), e1 = expf(s01 - m0);
    float in0 = 1.f / (e0 + e1);
    float w00 = e0 * in0, w01 = e1 * in0;
    float s10 = p10 * scale, s11 = p11 * scale;
    float m1 = fmaxf(s10, s11);
    float f0 = expf(s10 - m1), f1 = expf(s11 - m1);
    float in1 = 1.f / (f0 + f1);
    float w10 = f0 * in1, w11 = f1 * in1;

#pragma unroll
    for (int c = 0; c < 4; ++c) {
        int d = g + c * 32;
        xs[       hh * 128 + d] = w00 * v[0][c] + w01 * v[1][c];
        xs[1024 + hh * 128 + d] = w10 * v[0][c] + w11 * v[1][c];
    }
    __syncthreads();

    // 3) O-projection dot
    float acc[2][4] = {{0.f,0.f,0.f,0.f},{0.f,0.f,0.f,0.f}};
#pragma unroll
    for (int i = 0; i < 4; ++i) {
        int dd = d0 + i;
#pragma unroll
        for (int s = 0; s < 2; ++s) {
            float xv = xs[s * 1024 + dd];
            acc[s][0] += xv * wreg[i].x; acc[s][1] += xv * wreg[i].y;
            acc[s][2] += xv * wreg[i].z; acc[s][3] += xv * wreg[i].w;
        }
    }
    __syncthreads();
#pragma unroll
    for (int s = 0; s < 2; ++s)
#pragma unroll
        for (int c = 0; c < 4; ++c)
            xs[(dp * 2 + s) * 256 + lane * 4 + c] = acc[s][c];
    __syncthreads();
    for (int o = t; o < 512; o += 256) {
        int s = o >> 8, col = o & 255;
        float sum = 0.f;
#pragma unroll
        for (int p = 0; p < 4; ++p) sum += xs[(p * 2 + s) * 256 + col];
        atomicAdd(out + (size_t)s * 1024 + blockIdx.x * 256 + col, sum);
    }
}

// ---------------- down-proj GEMV with fused silu(gate)*up, residual into h ----------------
// grid: (4, 128). block 256. Each block: 256 cols x 32 f-rows.
__global__ __launch_bounds__(256) void gemv_down(
    const float* __restrict__ gu,  // [s][2][4096]
    const float* __restrict__ W,   // [4096][1024]
    float* __restrict__ out)       // h [2][1024]
{
    __shared__ float a[2][32];
    __shared__ float red[2048];
    const int t = threadIdx.x;
    const int lane = t & 63;
    const int dp = t >> 6;
    const int j = blockIdx.x * 256 + lane * 4;
    const int f0 = blockIdx.y * 32 + dp * 8;

    // 1) prefetch weight slab
    float4 wreg[8];
    const float* Wp = W + (size_t)f0 * 1024 + j;
#pragma unroll
    for (int i = 0; i < 8; ++i)
        wreg[i] = *reinterpret_cast<const float4*>(Wp + (size_t)i * 1024);

    // 2) silu(gate)*up for this block's 32 rows
    if (t < 64) {
        int s = t >> 5, x = t & 31;
        int f = blockIdx.y * 32 + x;
        float g = gu[s * 8192 + f];
        float u = gu[s * 8192 + 4096 + f];
        a[s][x] = g / (1.f + expf(-g)) * u;
    }
    __syncthreads();

    float acc[2][4] = {{0.f,0.f,0.f,0.f},{0.f,0.f,0.f,0.f}};
#pragma unroll
    for (int i = 0; i < 8; ++i) {
        int dl = dp * 8 + i;
#pragma unroll
        for (int s = 0; s < 2; ++s) {
            float xv = a[s][dl];
            acc[s][0] += xv * wreg[i].x; acc[s][1] += xv * wreg[i].y;
            acc[s][2] += xv * wreg[i].z; acc[s][3] += xv * wreg[i].w;
        }
    }
#pragma unroll
    for (int s = 0; s < 2; ++s)
#pragma unroll
        for (int c = 0; c < 4; ++c)
            red[(dp * 2 + s) * 256 + lane * 4 + c] = acc[s][c];
    __syncthreads();
    for (int o = t; o < 512; o += 256) {
        int s = o >> 8, col = o & 255;
        float sum = 0.f;
#pragma unroll
        for (int p = 0; p < 4; ++p) sum += red[(p * 2 + s) * 256 + col];
        atomicAdd(out + (size_t)s * 1024 + blockIdx.x * 256 + col, sum);
    }
}

extern "C" void kernel_launch(void* const* d_in, const int* in_sizes, int n_in,
                              void* d_out, int out_size, void* d_ws, size_t ws_size,
                              hipStream_t stream)
{
    const float* past_hidden = (const float*)d_in[0];
    const int*   cb0         = (const int*)d_in[1];
    const float* codec_emb   = (const float*)d_in[2];
    const float* Wq  = (const float*)d_in[3];
    const float* Wk  = (const float*)d_in[4];
    const float* Wv  = (const float*)d_in[5];
    const float* Wo  = (const float*)d_in[6];
    const float* qnw = (const float*)d_in[7];
    const float* knw = (const float*)d_in[8];
    const float* ln1 = (const float*)d_in[9];
    const float* ln2 = (const float*)d_in[10];
    const float* Wg  = (const float*)d_in[11];
    const float* Wu  = (const float*)d_in[12];
    const float* Wd  = (const float*)d_in[13];
    const float* fnw = (const float*)d_in[14];
    const float* lmh = (const float*)d_in[15];

    float* out = (float*)d_out;
    float* ws  = (float*)d_ws;
    float* h      = ws;             // 2048
    float* qkvb   = ws + 2048;      // 5*6144
    float* gub    = ws + 43008;     // 5*16384
    float* logits = out;            // 30720
    float* kvc    = out + 30720;    // 20480

    init_kernel<<<256, 256, 0, stream>>>(past_hidden, codec_emb, cb0, ws, logits);

    for (int l = 0; l < 5; ++l) {
        const float* wq = Wq + (size_t)l * 1024 * 1024;
        const float* wk = Wk + (size_t)l * 1024 * 1024;
        const float* wv = Wv + (size_t)l * 1024 * 1024;
        const float* wo = Wo + (size_t)l * 1024 * 1024;
        const float* wg = Wg + (size_t)l * 1024 * 4096;
        const float* wu = Wu + (size_t)l * 1024 * 4096;
        const float* wd = Wd + (size_t)l * 4096 * 1024;
        float* qkv = qkvb + (size_t)l * 6144;
        float* gu  = gub  + (size_t)l * 16384;

        // QKV projection with deferred rmsnorm(ln1): out[s][z*1024 + j]
        gemv_rms<2, 8><<<dim3(4, 32, 3), 256, 0, stream>>>(
            h, ln1 + l * 1024, wq, wk, wv, 0, qkv, 3072, 1024, 1024);
        // attention fused into O projection; residual-add into h; kv cache write
        attn_o_kernel<<<dim3(4, 64), 256, 0, stream>>>(
            qkv, qnw + l * 128, knw + l * 128, wo, h, kvc + (size_t)(2 * l) * 2048);
        // gate & up with deferred rmsnorm(ln2): out[s][z*4096 + f]
        gemv_rms<2, 8><<<dim3(16, 32, 2), 256, 0, stream>>>(
            h, ln2 + l * 1024, wg, wu, wu, 0, gu, 8192, 4096, 4096);
        // down proj with fused silu*up, residual-add into h
        gemv_down<<<dim3(4, 128), 256, 0, stream>>>(gu, wd, h);
    }

    // lm heads with fused (deferred) final rmsnorm: 15 x (1024 x 2048)
    gemv_rms<1, 16><<<dim3(8, 16, 15), 256, 0, stream>>>(
        h + 1024, fnw, lmh, nullptr, nullptr, (size_t)1024 * 2048,
        logits, 2048, 2048, 2048);
}